// Round 2
// baseline (2034.086 us; speedup 1.0000x reference)
//
#include <hip/hip_runtime.h>

#define N_NODES 102400
#define FEAT    400
#define F1      256
#define E_EDGES 4096000
#define NUM_G   256
#define NPG     400

// ---------------- degree count ----------------
__global__ __launch_bounds__(256) void k_count(const int* __restrict__ ei,
                                               int* __restrict__ cnt) {
    int e = blockIdx.x * 256 + threadIdx.x;
    int d = ei[E_EDGES + e];
    atomicAdd(&cnt[d], 1);
}

__global__ __launch_bounds__(256) void k_dis(const int* __restrict__ cnt,
                                             float* __restrict__ dis) {
    int i = blockIdx.x * 256 + threadIdx.x;
    dis[i] = rsqrtf((float)(cnt[i] + 1));   // +1 self-loop; always > 0
}

// ---------------- prefix sum (3-phase) ----------------
__global__ __launch_bounds__(1024) void k_scan1(const int* __restrict__ cnt,
                                                int* __restrict__ part,
                                                int* __restrict__ bsum) {
    __shared__ int s[1024];
    int t = threadIdx.x, b = blockIdx.x;
    int gid = b * 1024 + t;
    s[t] = cnt[gid];
    __syncthreads();
    for (int off = 1; off < 1024; off <<= 1) {
        int v = (t >= off) ? s[t - off] : 0;
        __syncthreads();
        s[t] += v;
        __syncthreads();
    }
    part[gid] = s[t];            // inclusive
    if (t == 1023) bsum[b] = s[t];
}

__global__ void k_scan2(int* __restrict__ bsum) {
    if (threadIdx.x == 0) {
        int run = 0;
        for (int i = 0; i < N_NODES / 1024; ++i) {
            int v = bsum[i]; bsum[i] = run; run += v;
        }
    }
}

__global__ __launch_bounds__(1024) void k_scan3(const int* __restrict__ cnt,
                                                const int* __restrict__ part,
                                                const int* __restrict__ bsum,
                                                int* __restrict__ row_start,
                                                int* __restrict__ cursor) {
    int t = threadIdx.x, b = blockIdx.x;
    int gid = b * 1024 + t;
    int inc = part[gid];
    int ex = inc - cnt[gid] + bsum[b];      // exclusive
    row_start[gid] = ex;
    cursor[gid] = ex;
    if (gid == N_NODES - 1) row_start[N_NODES] = inc + bsum[b];
}

// ---------------- CSR fill ----------------
__global__ __launch_bounds__(256) void k_fill(const int* __restrict__ ei,
                                              int* __restrict__ cursor,
                                              int* __restrict__ csr) {
    int e = blockIdx.x * 256 + threadIdx.x;
    int s = ei[e];
    int d = ei[E_EDGES + e];
    int pos = atomicAdd(&cursor[d], 1);
    csr[pos] = s;
}

// ---------------- fp32 tiled GEMM: C[M x 256] = A[M x K] @ B[K x 256] ----------------
#define BM 64
#define BN 64
#define BK 16
__global__ __launch_bounds__(256) void k_gemm(const float* __restrict__ A,
                                              const float* __restrict__ B,
                                              float* __restrict__ C, int K) {
    __shared__ float As[BK][BM];
    __shared__ float Bs[BK][BN];
    int t = threadIdx.x;
    int m0 = blockIdx.x * BM;
    int n0 = blockIdx.y * BN;
    int tx = t & 15, ty = t >> 4;
    int ar = t >> 2, ac = (t & 3) * 4;   // A tile load: row ar (0..63), cols ac..ac+3
    int br = t >> 4, bc = (t & 15) * 4;  // B tile load: row br (0..15), cols bc..bc+3
    float acc[4][4] = {};
    for (int k0 = 0; k0 < K; k0 += BK) {
        float4 av = *(const float4*)&A[(size_t)(m0 + ar) * K + k0 + ac];
        float4 bv = *(const float4*)&B[(size_t)(k0 + br) * 256 + n0 + bc];
        __syncthreads();
        As[ac + 0][ar] = av.x;
        As[ac + 1][ar] = av.y;
        As[ac + 2][ar] = av.z;
        As[ac + 3][ar] = av.w;
        *(float4*)&Bs[br][bc] = bv;
        __syncthreads();
#pragma unroll
        for (int k = 0; k < BK; ++k) {
            float4 a = *(const float4*)&As[k][ty * 4];
            float4 b = *(const float4*)&Bs[k][tx * 4];
            float af[4] = {a.x, a.y, a.z, a.w};
            float bf[4] = {b.x, b.y, b.z, b.w};
#pragma unroll
            for (int i = 0; i < 4; ++i)
#pragma unroll
                for (int j = 0; j < 4; ++j)
                    acc[i][j] = fmaf(af[i], bf[j], acc[i][j]);
        }
    }
#pragma unroll
    for (int i = 0; i < 4; ++i) {
        float4 v = make_float4(acc[i][0], acc[i][1], acc[i][2], acc[i][3]);
        *(float4*)&C[(size_t)(m0 + ty * 4 + i) * 256 + n0 + tx * 4] = v;
    }
}

// ---------------- normalized gather-aggregation (+bias, +optional relu) ----------------
__global__ __launch_bounds__(256) void k_agg(const float* __restrict__ h,
                                             const float* __restrict__ dis,
                                             const int* __restrict__ row_start,
                                             const int* __restrict__ csr,
                                             const float* __restrict__ bias,
                                             float* __restrict__ out, int do_relu) {
    int i = blockIdx.x;
    int t = threadIdx.x;
    __shared__ int   s_src[256];
    __shared__ float s_nrm[256];
    float di = dis[i];
    float acc = h[(size_t)i * F1 + t] * di * di;   // self-loop
    int beg = row_start[i], end = row_start[i + 1];
    for (int base = beg; base < end; base += 256) {
        int m = min(256, end - base);
        __syncthreads();
        if (t < m) {
            int s = csr[base + t];
            s_src[t] = s;
            s_nrm[t] = dis[s] * di;
        }
        __syncthreads();
        for (int j = 0; j < m; ++j)
            acc = fmaf(h[(size_t)s_src[j] * F1 + t], s_nrm[j], acc);
    }
    acc += bias[t];
    if (do_relu) acc = fmaxf(acc, 0.f);
    out[(size_t)i * F1 + t] = acc;
}

// ---------------- mean|max readout + final linear ----------------
__global__ __launch_bounds__(256) void k_readout(const float* __restrict__ h2,
                                                 const float* __restrict__ Wm,
                                                 const float* __restrict__ bm,
                                                 float* __restrict__ out) {
    int g = blockIdx.x, t = threadIdx.x;
    const float* base = h2 + (size_t)g * NPG * F1;
    float sum = 0.f, mx = -3.402823466e38f;
    for (int r = 0; r < NPG; ++r) {
        float v = base[(size_t)r * F1 + t];
        sum += v;
        mx = fmaxf(mx, v);
    }
    float mean = sum * (1.0f / NPG);
    float p0 = mean * Wm[t * 2 + 0] + mx * Wm[(F1 + t) * 2 + 0];
    float p1 = mean * Wm[t * 2 + 1] + mx * Wm[(F1 + t) * 2 + 1];
    __shared__ float2 red[256];
    red[t] = make_float2(p0, p1);
    __syncthreads();
    for (int s2 = 128; s2 > 0; s2 >>= 1) {
        if (t < s2) {
            red[t].x += red[t + s2].x;
            red[t].y += red[t + s2].y;
        }
        __syncthreads();
    }
    if (t == 0) {
        out[g * 2 + 0] = red[0].x + bm[0];
        out[g * 2 + 1] = red[0].y + bm[1];
    }
}

extern "C" void kernel_launch(void* const* d_in, const int* in_sizes, int n_in,
                              void* d_out, int out_size, void* d_ws, size_t ws_size,
                              hipStream_t stream) {
    const float* x  = (const float*)d_in[0];
    const int*   ei = (const int*)d_in[1];   // int64 in reference -> int32 on device
    // d_in[2] = batch (int32, unused: batch = node/400), d_in[3] = num_graphs (unused)
    const float* W1 = (const float*)d_in[4];
    const float* b1 = (const float*)d_in[5];
    const float* W2 = (const float*)d_in[6];
    const float* b2 = (const float*)d_in[7];
    const float* Wm = (const float*)d_in[8];
    const float* bm = (const float*)d_in[9];
    float* out = (float*)d_out;

    char* ws = (char*)d_ws;
    size_t off = 0;
    auto alloc = [&](size_t bytes) {
        void* p = ws + off;
        off = (off + bytes + 255) & ~(size_t)255;
        return p;
    };
    int*   cnt       = (int*)alloc((size_t)N_NODES * 4);
    int*   part      = (int*)alloc((size_t)N_NODES * 4);
    int*   bsum      = (int*)alloc(512);
    int*   row_start = (int*)alloc((size_t)(N_NODES + 1) * 4);
    int*   cursor    = (int*)alloc((size_t)N_NODES * 4);
    float* dis       = (float*)alloc((size_t)N_NODES * 4);
    int*   csr       = (int*)alloc((size_t)E_EDGES * 4);
    float* bufA      = (float*)alloc((size_t)N_NODES * F1 * 4);
    float* bufB      = (float*)alloc((size_t)N_NODES * F1 * 4);

    hipMemsetAsync(cnt, 0, (size_t)N_NODES * 4, stream);
    k_count<<<E_EDGES / 256, 256, 0, stream>>>(ei, cnt);
    k_dis<<<N_NODES / 256, 256, 0, stream>>>(cnt, dis);
    k_scan1<<<N_NODES / 1024, 1024, 0, stream>>>(cnt, part, bsum);
    k_scan2<<<1, 64, 0, stream>>>(bsum);
    k_scan3<<<N_NODES / 1024, 1024, 0, stream>>>(cnt, part, bsum, row_start, cursor);
    k_fill<<<E_EDGES / 256, 256, 0, stream>>>(ei, cursor, csr);

    dim3 gg(N_NODES / BM, F1 / BN);
    k_gemm<<<gg, 256, 0, stream>>>(x, W1, bufA, FEAT);                          // h = x@W1
    k_agg<<<N_NODES, 256, 0, stream>>>(bufA, dis, row_start, csr, b1, bufB, 1); // relu(Agg+b1)
    k_gemm<<<gg, 256, 0, stream>>>(bufB, W2, bufA, F1);                         // h1@W2
    k_agg<<<N_NODES, 256, 0, stream>>>(bufA, dis, row_start, csr, b2, bufB, 0); // Agg+b2
    k_readout<<<NUM_G, 256, 0, stream>>>(bufB, Wm, bm, out);
}

// Round 3
// 1496.839 us; speedup vs baseline: 1.3589x; 1.3589x over previous
//
#include <hip/hip_runtime.h>
#include <hip/hip_bf16.h>

#define N_NODES 102400
#define FEAT    400
#define F1      256
#define E_EDGES 4096000
#define NUM_G   256
#define NPG     400

// ---------------- degree count ----------------
__global__ __launch_bounds__(256) void k_count(const int* __restrict__ ei,
                                               int* __restrict__ cnt) {
    int e = blockIdx.x * 256 + threadIdx.x;
    int d = ei[E_EDGES + e];
    atomicAdd(&cnt[d], 1);
}

__global__ __launch_bounds__(256) void k_dis(const int* __restrict__ cnt,
                                             float* __restrict__ dis) {
    int i = blockIdx.x * 256 + threadIdx.x;
    dis[i] = rsqrtf((float)(cnt[i] + 1));   // +1 self-loop; always > 0
}

// ---------------- prefix sum (3-phase) ----------------
__global__ __launch_bounds__(1024) void k_scan1(const int* __restrict__ cnt,
                                                int* __restrict__ part,
                                                int* __restrict__ bsum) {
    __shared__ int s[1024];
    int t = threadIdx.x, b = blockIdx.x;
    int gid = b * 1024 + t;
    s[t] = cnt[gid];
    __syncthreads();
    for (int off = 1; off < 1024; off <<= 1) {
        int v = (t >= off) ? s[t - off] : 0;
        __syncthreads();
        s[t] += v;
        __syncthreads();
    }
    part[gid] = s[t];            // inclusive
    if (t == 1023) bsum[b] = s[t];
}

__global__ void k_scan2(int* __restrict__ bsum) {
    if (threadIdx.x == 0) {
        int run = 0;
        for (int i = 0; i < N_NODES / 1024; ++i) {
            int v = bsum[i]; bsum[i] = run; run += v;
        }
    }
}

__global__ __launch_bounds__(1024) void k_scan3(const int* __restrict__ cnt,
                                                const int* __restrict__ part,
                                                const int* __restrict__ bsum,
                                                int* __restrict__ row_start,
                                                int* __restrict__ cursor) {
    int t = threadIdx.x, b = blockIdx.x;
    int gid = b * 1024 + t;
    int inc = part[gid];
    int ex = inc - cnt[gid] + bsum[b];      // exclusive
    row_start[gid] = ex;
    cursor[gid] = ex;
    if (gid == N_NODES - 1) row_start[N_NODES] = inc + bsum[b];
}

// ---------------- CSR fill ----------------
__global__ __launch_bounds__(256) void k_fill(const int* __restrict__ ei,
                                              int* __restrict__ cursor,
                                              int* __restrict__ csr) {
    int e = blockIdx.x * 256 + threadIdx.x;
    int s = ei[e];
    int d = ei[E_EDGES + e];
    int pos = atomicAdd(&cursor[d], 1);
    csr[pos] = s;
}

// ---------------- fp32 tiled GEMM -> bf16 out: C[M x 256] = A[M x K] @ B[K x 256] ----------------
#define BM 64
#define BN 64
#define BK 16
__global__ __launch_bounds__(256) void k_gemm(const float* __restrict__ A,
                                              const float* __restrict__ B,
                                              __hip_bfloat162* __restrict__ C, int K) {
    __shared__ float As[BK][BM];
    __shared__ float Bs[BK][BN];
    int t = threadIdx.x;
    int m0 = blockIdx.x * BM;
    int n0 = blockIdx.y * BN;
    int tx = t & 15, ty = t >> 4;
    int ar = t >> 2, ac = (t & 3) * 4;   // A tile load: row ar (0..63), cols ac..ac+3
    int br = t >> 4, bc = (t & 15) * 4;  // B tile load: row br (0..15), cols bc..bc+3
    float acc[4][4] = {};
    for (int k0 = 0; k0 < K; k0 += BK) {
        float4 av = *(const float4*)&A[(size_t)(m0 + ar) * K + k0 + ac];
        float4 bv = *(const float4*)&B[(size_t)(k0 + br) * 256 + n0 + bc];
        __syncthreads();
        As[ac + 0][ar] = av.x;
        As[ac + 1][ar] = av.y;
        As[ac + 2][ar] = av.z;
        As[ac + 3][ar] = av.w;
        *(float4*)&Bs[br][bc] = bv;
        __syncthreads();
#pragma unroll
        for (int k = 0; k < BK; ++k) {
            float4 a = *(const float4*)&As[k][ty * 4];
            float4 b = *(const float4*)&Bs[k][tx * 4];
            float af[4] = {a.x, a.y, a.z, a.w};
            float bf[4] = {b.x, b.y, b.z, b.w};
#pragma unroll
            for (int i = 0; i < 4; ++i)
#pragma unroll
                for (int j = 0; j < 4; ++j)
                    acc[i][j] = fmaf(af[i], bf[j], acc[i][j]);
        }
    }
#pragma unroll
    for (int i = 0; i < 4; ++i) {
        // row m0+ty*4+i, cols n0+tx*4 .. +3  -> two packed bf162 (8B)
        size_t idx = (size_t)(m0 + ty * 4 + i) * 128 + (n0 >> 1) + tx * 2;
        C[idx]     = __float22bfloat162_rn(make_float2(acc[i][0], acc[i][1]));
        C[idx + 1] = __float22bfloat162_rn(make_float2(acc[i][2], acc[i][3]));
    }
}

// ---------------- normalized gather-aggregation over bf16 rows ----------------
// one block (128 threads) per dst node; lane t handles features [2t, 2t+1]
__global__ __launch_bounds__(128) void k_agg(const __hip_bfloat162* __restrict__ h,
                                             const float* __restrict__ dis,
                                             const int* __restrict__ row_start,
                                             const int* __restrict__ csr,
                                             const float* __restrict__ bias,
                                             float2* __restrict__ out, int do_relu) {
    int i = blockIdx.x;
    int t = threadIdx.x;
    __shared__ int   s_src[128];
    __shared__ float s_nrm[128];
    float di = dis[i];
    float2 self = __bfloat1622float2(h[(size_t)i * 128 + t]);
    float accx = self.x * di * di;
    float accy = self.y * di * di;
    int beg = row_start[i], end = row_start[i + 1];
    for (int base = beg; base < end; base += 128) {
        int m = min(128, end - base);
        __syncthreads();
        if (t < m) {
            int s = csr[base + t];
            s_src[t] = s;
            s_nrm[t] = dis[s] * di;
        }
        __syncthreads();
        for (int j = 0; j < m; ++j) {
            float2 v = __bfloat1622float2(h[(size_t)s_src[j] * 128 + t]);
            float w = s_nrm[j];
            accx = fmaf(v.x, w, accx);
            accy = fmaf(v.y, w, accy);
        }
    }
    const float2* b2 = (const float2*)bias;
    float2 bb = b2[t];
    accx += bb.x;
    accy += bb.y;
    if (do_relu) {
        accx = fmaxf(accx, 0.f);
        accy = fmaxf(accy, 0.f);
    }
    out[(size_t)i * 128 + t] = make_float2(accx, accy);
}

// ---------------- mean|max readout + final linear ----------------
__global__ __launch_bounds__(256) void k_readout(const float* __restrict__ h2,
                                                 const float* __restrict__ Wm,
                                                 const float* __restrict__ bm,
                                                 float* __restrict__ out) {
    int g = blockIdx.x, t = threadIdx.x;
    const float* base = h2 + (size_t)g * NPG * F1;
    float sum = 0.f, mx = -3.402823466e38f;
    for (int r = 0; r < NPG; ++r) {
        float v = base[(size_t)r * F1 + t];
        sum += v;
        mx = fmaxf(mx, v);
    }
    float mean = sum * (1.0f / NPG);
    float p0 = mean * Wm[t * 2 + 0] + mx * Wm[(F1 + t) * 2 + 0];
    float p1 = mean * Wm[t * 2 + 1] + mx * Wm[(F1 + t) * 2 + 1];
    __shared__ float2 red[256];
    red[t] = make_float2(p0, p1);
    __syncthreads();
    for (int s2 = 128; s2 > 0; s2 >>= 1) {
        if (t < s2) {
            red[t].x += red[t + s2].x;
            red[t].y += red[t + s2].y;
        }
        __syncthreads();
    }
    if (t == 0) {
        out[g * 2 + 0] = red[0].x + bm[0];
        out[g * 2 + 1] = red[0].y + bm[1];
    }
}

extern "C" void kernel_launch(void* const* d_in, const int* in_sizes, int n_in,
                              void* d_out, int out_size, void* d_ws, size_t ws_size,
                              hipStream_t stream) {
    const float* x  = (const float*)d_in[0];
    const int*   ei = (const int*)d_in[1];   // int64 in reference -> int32 on device
    // d_in[2] = batch (unused: batch = node/400), d_in[3] = num_graphs (unused)
    const float* W1 = (const float*)d_in[4];
    const float* b1 = (const float*)d_in[5];
    const float* W2 = (const float*)d_in[6];
    const float* b2 = (const float*)d_in[7];
    const float* Wm = (const float*)d_in[8];
    const float* bm = (const float*)d_in[9];
    float* out = (float*)d_out;

    char* ws = (char*)d_ws;
    size_t off = 0;
    auto alloc = [&](size_t bytes) {
        void* p = ws + off;
        off = (off + bytes + 255) & ~(size_t)255;
        return p;
    };
    int*   cnt       = (int*)alloc((size_t)N_NODES * 4);
    int*   part      = (int*)alloc((size_t)N_NODES * 4);
    int*   bsum      = (int*)alloc(512);
    int*   row_start = (int*)alloc((size_t)(N_NODES + 1) * 4);
    int*   cursor    = (int*)alloc((size_t)N_NODES * 4);
    float* dis       = (float*)alloc((size_t)N_NODES * 4);
    int*   csr       = (int*)alloc((size_t)E_EDGES * 4);
    float*            Pf = (float*)alloc((size_t)N_NODES * F1 * 4);            // fp32 ping
    __hip_bfloat162*  Pb = (__hip_bfloat162*)alloc((size_t)N_NODES * F1 * 2);  // bf16 pong

    hipMemsetAsync(cnt, 0, (size_t)N_NODES * 4, stream);
    k_count<<<E_EDGES / 256, 256, 0, stream>>>(ei, cnt);
    k_dis<<<N_NODES / 256, 256, 0, stream>>>(cnt, dis);
    k_scan1<<<N_NODES / 1024, 1024, 0, stream>>>(cnt, part, bsum);
    k_scan2<<<1, 64, 0, stream>>>(bsum);
    k_scan3<<<N_NODES / 1024, 1024, 0, stream>>>(cnt, part, bsum, row_start, cursor);
    k_fill<<<E_EDGES / 256, 256, 0, stream>>>(ei, cursor, csr);

    dim3 gg(N_NODES / BM, F1 / BN);
    k_gemm<<<gg, 256, 0, stream>>>(x, W1, Pb, FEAT);                                  // bf16(x@W1)
    k_agg<<<N_NODES, 128, 0, stream>>>(Pb, dis, row_start, csr, b1, (float2*)Pf, 1);  // relu(Agg+b1) fp32
    k_gemm<<<gg, 256, 0, stream>>>(Pf, W2, Pb, F1);                                   // bf16(h1@W2)
    k_agg<<<N_NODES, 128, 0, stream>>>(Pb, dis, row_start, csr, b2, (float2*)Pf, 0);  // Agg+b2 fp32
    k_readout<<<NUM_G, 256, 0, stream>>>(Pf, Wm, bm, out);
}

// Round 4
// 1043.350 us; speedup vs baseline: 1.9496x; 1.4346x over previous
//
#include <hip/hip_runtime.h>
#include <hip/hip_bf16.h>

#define N_NODES 102400
#define FEAT    400
#define F1      256
#define E_EDGES 4096000
#define NUM_G   256
#define NPG     400

typedef __attribute__((ext_vector_type(8))) short bfrag;   // 8 bf16 (4 VGPR)
typedef __attribute__((ext_vector_type(4))) float ffrag;   // 4 fp32 acc

__device__ inline short f2b(float f) {
    __hip_bfloat16 h = __float2bfloat16(f);
    return *reinterpret_cast<short*>(&h);
}

// ---------------- degree count + per-edge rank ----------------
__global__ __launch_bounds__(256) void k_count(const int* __restrict__ ei,
                                               int* __restrict__ cnt,
                                               int* __restrict__ rank) {
    int e = blockIdx.x * 256 + threadIdx.x;
    int d = ei[E_EDGES + e];
    rank[e] = atomicAdd(&cnt[d], 1);
}

__global__ __launch_bounds__(256) void k_dis(const int* __restrict__ cnt,
                                             float* __restrict__ dis) {
    int i = blockIdx.x * 256 + threadIdx.x;
    dis[i] = rsqrtf((float)(cnt[i] + 1));   // +1 self-loop; always > 0
}

// ---------------- prefix sum (3-phase) ----------------
__global__ __launch_bounds__(1024) void k_scan1(const int* __restrict__ cnt,
                                                int* __restrict__ part,
                                                int* __restrict__ bsum) {
    __shared__ int s[1024];
    int t = threadIdx.x, b = blockIdx.x;
    int gid = b * 1024 + t;
    s[t] = cnt[gid];
    __syncthreads();
    for (int off = 1; off < 1024; off <<= 1) {
        int v = (t >= off) ? s[t - off] : 0;
        __syncthreads();
        s[t] += v;
        __syncthreads();
    }
    part[gid] = s[t];            // inclusive
    if (t == 1023) bsum[b] = s[t];
}

__global__ void k_scan2(int* __restrict__ bsum) {
    if (threadIdx.x == 0) {
        int run = 0;
        for (int i = 0; i < N_NODES / 1024; ++i) {
            int v = bsum[i]; bsum[i] = run; run += v;
        }
    }
}

__global__ __launch_bounds__(1024) void k_scan3(const int* __restrict__ cnt,
                                                const int* __restrict__ part,
                                                const int* __restrict__ bsum,
                                                int* __restrict__ row_start) {
    int t = threadIdx.x, b = blockIdx.x;
    int gid = b * 1024 + t;
    int inc = part[gid];
    int ex = inc - cnt[gid] + bsum[b];      // exclusive
    row_start[gid] = ex;
    if (gid == N_NODES - 1) row_start[N_NODES] = inc + bsum[b];
}

// ---------------- CSR fill (no atomics: rank precomputed) ----------------
__global__ __launch_bounds__(256) void k_fill(const int* __restrict__ ei,
                                              const int* __restrict__ rank,
                                              const int* __restrict__ row_start,
                                              int* __restrict__ csr) {
    int e = blockIdx.x * 256 + threadIdx.x;
    int s = ei[e];
    int d = ei[E_EDGES + e];
    csr[row_start[d] + rank[e]] = s;
}

// ---------------- weight transpose+pad to bf16: Wt[256][Kpad] from W[Kreal][256] ----------------
__global__ __launch_bounds__(256) void k_cvt_w(const float* __restrict__ W,
                                               short* __restrict__ Wt,
                                               int Kreal, int Kpad) {
    int idx = blockIdx.x * 256 + threadIdx.x;
    if (idx >= 256 * Kpad) return;
    int n = idx / Kpad, k = idx - n * Kpad;
    float v = (k < Kreal) ? W[(size_t)k * 256 + n] : 0.f;
    Wt[idx] = f2b(v);
}

// ---------------- bf16 MFMA GEMM: C[M x 256](bf16) = A[M x K] @ Wt^T ----------------
// 128x128 tile, BK=32, 256 thr = 4 waves (2x2), 64x64 per wave = 4x4 frags 16x16x32
template<bool AF32>
__global__ __launch_bounds__(256) void k_mm(const void* __restrict__ Ap,
                                            const short* __restrict__ Wt, // [256][Kpad] bf16
                                            int Kreal, int Kpad,
                                            short* __restrict__ C) {     // [M][256] bf16
    __shared__ short As[128][40];   // rows m, cols k (pad 40 -> 80B stride, 16B aligned)
    __shared__ short Bs[128][40];   // rows n, cols k
    const int t    = threadIdx.x;
    const int lane = t & 63;
    const int w    = t >> 6;
    const int wm   = w >> 1, wn = w & 1;
    const int m0   = blockIdx.x * 128;
    const int n0   = blockIdx.y * 128;

    const int sr = t >> 1;           // staged row 0..127
    const int sh = (t & 1) * 16;     // k-half 0 / 16

    ffrag acc[4][4];
#pragma unroll
    for (int i = 0; i < 4; ++i)
#pragma unroll
        for (int j = 0; j < 4; ++j) {
            ffrag z = {0.f, 0.f, 0.f, 0.f};
            acc[i][j] = z;
        }

    const int rl = lane & 15;
    const int kc = (lane >> 4) * 8;

    for (int k0 = 0; k0 < Kpad; k0 += 32) {
        short av[16], bv[16];
        if constexpr (AF32) {
            const float* A = (const float*)Ap;
            const float* arow = A + (size_t)(m0 + sr) * Kreal + k0 + sh;
#pragma unroll
            for (int c = 0; c < 4; ++c) {
                float4 v;
                if (k0 + sh + c * 4 < Kreal) v = *(const float4*)(arow + c * 4);
                else                         v = make_float4(0.f, 0.f, 0.f, 0.f);
                av[c * 4 + 0] = f2b(v.x);
                av[c * 4 + 1] = f2b(v.y);
                av[c * 4 + 2] = f2b(v.z);
                av[c * 4 + 3] = f2b(v.w);
            }
        } else {
            const short* A = (const short*)Ap;
            const short* arow = A + (size_t)(m0 + sr) * Kpad + k0 + sh;
            *(bfrag*)&av[0] = *(const bfrag*)arow;
            *(bfrag*)&av[8] = *(const bfrag*)(arow + 8);
        }
        const short* brow = Wt + (size_t)(n0 + sr) * Kpad + k0 + sh;
        *(bfrag*)&bv[0] = *(const bfrag*)brow;
        *(bfrag*)&bv[8] = *(const bfrag*)(brow + 8);

        __syncthreads();
        *(bfrag*)&As[sr][sh]     = *(bfrag*)&av[0];
        *(bfrag*)&As[sr][sh + 8] = *(bfrag*)&av[8];
        *(bfrag*)&Bs[sr][sh]     = *(bfrag*)&bv[0];
        *(bfrag*)&Bs[sr][sh + 8] = *(bfrag*)&bv[8];
        __syncthreads();

        bfrag a[4], b[4];
#pragma unroll
        for (int i = 0; i < 4; ++i) a[i] = *(const bfrag*)&As[wm * 64 + i * 16 + rl][kc];
#pragma unroll
        for (int j = 0; j < 4; ++j) b[j] = *(const bfrag*)&Bs[wn * 64 + j * 16 + rl][kc];
#pragma unroll
        for (int i = 0; i < 4; ++i)
#pragma unroll
            for (int j = 0; j < 4; ++j)
                acc[i][j] = __builtin_amdgcn_mfma_f32_16x16x32_bf16(a[i], b[j], acc[i][j], 0, 0, 0);
    }

    const int rh = lane >> 4;
#pragma unroll
    for (int i = 0; i < 4; ++i)
#pragma unroll
        for (int j = 0; j < 4; ++j) {
            int col  = n0 + wn * 64 + j * 16 + rl;
            int rowb = m0 + wm * 64 + i * 16 + rh * 4;
#pragma unroll
            for (int q = 0; q < 4; ++q)
                C[(size_t)(rowb + q) * 256 + col] = f2b(acc[i][j][q]);
        }
}

// ---------------- normalized gather-aggregation over bf16 rows ----------------
// one block (128 threads) per dst node; lane t handles features [2t, 2t+1]
// layer1: +relu, bf16 output (feeds GEMM2). else: fp32 output (feeds readout)
__global__ __launch_bounds__(128) void k_agg(const __hip_bfloat162* __restrict__ h,
                                             const float* __restrict__ dis,
                                             const int* __restrict__ row_start,
                                             const int* __restrict__ csr,
                                             const float* __restrict__ bias,
                                             void* __restrict__ outp, int layer1) {
    int i = blockIdx.x;
    int t = threadIdx.x;
    __shared__ int   s_src[128];
    __shared__ float s_nrm[128];
    float di = dis[i];
    float2 self = __bfloat1622float2(h[(size_t)i * 128 + t]);
    float accx = self.x * di * di;
    float accy = self.y * di * di;
    int beg = row_start[i], end = row_start[i + 1];
    for (int base = beg; base < end; base += 128) {
        int m = min(128, end - base);
        __syncthreads();
        if (t < m) {
            int s = csr[base + t];
            s_src[t] = s;
            s_nrm[t] = dis[s] * di;
        }
        __syncthreads();
        for (int j = 0; j < m; ++j) {
            float2 v = __bfloat1622float2(h[(size_t)s_src[j] * 128 + t]);
            float w = s_nrm[j];
            accx = fmaf(v.x, w, accx);
            accy = fmaf(v.y, w, accy);
        }
    }
    const float2* b2 = (const float2*)bias;
    float2 bb = b2[t];
    accx += bb.x;
    accy += bb.y;
    if (layer1) {
        accx = fmaxf(accx, 0.f);
        accy = fmaxf(accy, 0.f);
        ((__hip_bfloat162*)outp)[(size_t)i * 128 + t] =
            __float22bfloat162_rn(make_float2(accx, accy));
    } else {
        ((float2*)outp)[(size_t)i * 128 + t] = make_float2(accx, accy);
    }
}

// ---------------- mean|max readout + final linear ----------------
__global__ __launch_bounds__(256) void k_readout(const float* __restrict__ h2,
                                                 const float* __restrict__ Wm,
                                                 const float* __restrict__ bm,
                                                 float* __restrict__ out) {
    int g = blockIdx.x, t = threadIdx.x;
    const float* base = h2 + (size_t)g * NPG * F1;
    float sum = 0.f, mx = -3.402823466e38f;
    for (int r = 0; r < NPG; ++r) {
        float v = base[(size_t)r * F1 + t];
        sum += v;
        mx = fmaxf(mx, v);
    }
    float mean = sum * (1.0f / NPG);
    float p0 = mean * Wm[t * 2 + 0] + mx * Wm[(F1 + t) * 2 + 0];
    float p1 = mean * Wm[t * 2 + 1] + mx * Wm[(F1 + t) * 2 + 1];
    __shared__ float2 red[256];
    red[t] = make_float2(p0, p1);
    __syncthreads();
    for (int s2 = 128; s2 > 0; s2 >>= 1) {
        if (t < s2) {
            red[t].x += red[t + s2].x;
            red[t].y += red[t + s2].y;
        }
        __syncthreads();
    }
    if (t == 0) {
        out[g * 2 + 0] = red[0].x + bm[0];
        out[g * 2 + 1] = red[0].y + bm[1];
    }
}

extern "C" void kernel_launch(void* const* d_in, const int* in_sizes, int n_in,
                              void* d_out, int out_size, void* d_ws, size_t ws_size,
                              hipStream_t stream) {
    const float* x  = (const float*)d_in[0];
    const int*   ei = (const int*)d_in[1];   // int64 in reference -> int32 on device
    // d_in[2] = batch (unused: batch = node/400), d_in[3] = num_graphs (unused)
    const float* W1 = (const float*)d_in[4];
    const float* b1 = (const float*)d_in[5];
    const float* W2 = (const float*)d_in[6];
    const float* b2 = (const float*)d_in[7];
    const float* Wm = (const float*)d_in[8];
    const float* bm = (const float*)d_in[9];
    float* out = (float*)d_out;

    char* ws = (char*)d_ws;
    size_t off = 0;
    auto alloc = [&](size_t bytes) {
        void* p = ws + off;
        off = (off + bytes + 255) & ~(size_t)255;
        return p;
    };
    int*   cnt       = (int*)alloc((size_t)N_NODES * 4);
    int*   part      = (int*)alloc((size_t)N_NODES * 4);
    int*   bsum      = (int*)alloc(512);
    int*   row_start = (int*)alloc((size_t)(N_NODES + 1) * 4);
    float* dis       = (float*)alloc((size_t)N_NODES * 4);
    int*   rank      = (int*)alloc((size_t)E_EDGES * 4);
    int*   csr       = (int*)alloc((size_t)E_EDGES * 4);
    short* Wt1       = (short*)alloc((size_t)256 * 416 * 2);
    short* Wt2       = (short*)alloc((size_t)256 * 256 * 2);
    short* Pb1       = (short*)alloc((size_t)N_NODES * F1 * 2);   // bf16 ping (gemm out)
    float* Pf        = (float*)alloc((size_t)N_NODES * F1 * 4);   // fp32 final; first half doubles as Pb2
    short* Pb2       = (short*)Pf;                                // bf16 pong (agg1 out), dead before agg2 writes Pf

    hipMemsetAsync(cnt, 0, (size_t)N_NODES * 4, stream);
    k_count<<<E_EDGES / 256, 256, 0, stream>>>(ei, cnt, rank);
    k_dis<<<N_NODES / 256, 256, 0, stream>>>(cnt, dis);
    k_scan1<<<N_NODES / 1024, 1024, 0, stream>>>(cnt, part, bsum);
    k_scan2<<<1, 64, 0, stream>>>(bsum);
    k_scan3<<<N_NODES / 1024, 1024, 0, stream>>>(cnt, part, bsum, row_start);
    k_fill<<<E_EDGES / 256, 256, 0, stream>>>(ei, rank, row_start, csr);

    k_cvt_w<<<(256 * 416 + 255) / 256, 256, 0, stream>>>(W1, Wt1, 400, 416);
    k_cvt_w<<<(256 * 256 + 255) / 256, 256, 0, stream>>>(W2, Wt2, 256, 256);

    dim3 gg(N_NODES / 128, 2);
    k_mm<true><<<gg, 256, 0, stream>>>((const void*)x, Wt1, 400, 416, Pb1);   // bf16(x@W1)
    k_agg<<<N_NODES, 128, 0, stream>>>((const __hip_bfloat162*)Pb1, dis, row_start, csr,
                                       b1, (void*)Pb2, 1);                    // relu(Agg+b1) -> bf16
    k_mm<false><<<gg, 256, 0, stream>>>((const void*)Pb2, Wt2, 256, 256, Pb1); // bf16(h1@W2)
    k_agg<<<N_NODES, 128, 0, stream>>>((const __hip_bfloat162*)Pb1, dis, row_start, csr,
                                       b2, (void*)Pf, 0);                     // Agg+b2 -> fp32
    k_readout<<<NUM_G, 256, 0, stream>>>(Pf, Wm, bm, out);
}